// Round 2
// baseline (1178.558 us; speedup 1.0000x reference)
//
#include <hip/hip_runtime.h>

// Graphormer layer, MI355X round 2: coalesced attention (LDS-staged bias/K/V).
// N=4096, D=512, H=8, DH=64, F=2048. fp32 in/out, bf16 MFMA internally.

typedef float f32x4 __attribute__((ext_vector_type(4)));
typedef short s8v  __attribute__((ext_vector_type(8)));   // 8 bf16 in 4 VGPRs
typedef unsigned short u16;

#define MFMA16(a,b,c) __builtin_amdgcn_mfma_f32_16x16x32_bf16((a),(b),(c),0,0,0)

static constexpr int N  = 4096;
static constexpr int D  = 512;
static constexpr int H  = 8;
static constexpr int DH = 64;
static constexpr int F  = 2048;
static constexpr int QKVW = 3 * D;       // 1536
static constexpr int NH   = N * H;       // 32768 (bias row stride in floats)
static constexpr int MT   = 32;          // attention m-tile
static constexpr int ATTN_LDS = 16384 + 32768 + 32768 + 8192;  // 90112 B

__device__ inline u16 f2bf(float f) {
  union { float f; unsigned u; } x; x.f = f;
  unsigned r = x.u + 0x7fffu + ((x.u >> 16) & 1u);
  return (u16)(r >> 16);
}

// ---------------- LayerNorm: fp32 (N,512) -> bf16 (N,512) ----------------
__global__ __launch_bounds__(256) void ln_kernel(const float* __restrict__ x,
                                                 const float* __restrict__ g,
                                                 const float* __restrict__ b,
                                                 u16* __restrict__ out) {
  const int row  = blockIdx.x * 4 + (threadIdx.x >> 6);
  const int lane = threadIdx.x & 63;
  const float4* xr = (const float4*)(x + (size_t)row * D);
  float4 v0 = xr[lane], v1 = xr[64 + lane];
  float s  = v0.x + v0.y + v0.z + v0.w + v1.x + v1.y + v1.z + v1.w;
  float ss = v0.x*v0.x + v0.y*v0.y + v0.z*v0.z + v0.w*v0.w
           + v1.x*v1.x + v1.y*v1.y + v1.z*v1.z + v1.w*v1.w;
  for (int off = 1; off < 64; off <<= 1) {
    s  += __shfl_xor(s,  off);
    ss += __shfl_xor(ss, off);
  }
  const float mu   = s * (1.0f / D);
  const float var  = ss * (1.0f / D) - mu * mu;
  const float rstd = rsqrtf(var + 1e-5f);
  const float4* g4 = (const float4*)g;
  const float4* b4 = (const float4*)b;
  float4 g0 = g4[lane], g1 = g4[64 + lane];
  float4 b0 = b4[lane], b1 = b4[64 + lane];
  u16* orow = out + (size_t)row * D;
  ushort4 o0, o1;
  o0.x = f2bf((v0.x - mu) * rstd * g0.x + b0.x);
  o0.y = f2bf((v0.y - mu) * rstd * g0.y + b0.y);
  o0.z = f2bf((v0.z - mu) * rstd * g0.z + b0.z);
  o0.w = f2bf((v0.w - mu) * rstd * g0.w + b0.w);
  o1.x = f2bf((v1.x - mu) * rstd * g1.x + b1.x);
  o1.y = f2bf((v1.y - mu) * rstd * g1.y + b1.y);
  o1.z = f2bf((v1.z - mu) * rstd * g1.z + b1.z);
  o1.w = f2bf((v1.w - mu) * rstd * g1.w + b1.w);
  ((ushort4*)orow)[lane]      = o0;
  ((ushort4*)orow)[64 + lane] = o1;
}

// ------------- weight transpose fp32 (R,C) -> bf16 (C,R) ----------------
__global__ void transpose_w(const float* __restrict__ src, u16* __restrict__ dst,
                            int R, int C) {
  int idx = blockIdx.x * 256 + threadIdx.x;
  if (idx < R * C) {
    int r = idx / C, c = idx - r * C;
    dst[(size_t)c * R + r] = f2bf(src[idx]);
  }
}

__global__ void pack_bqkv(const float* __restrict__ bq, const float* __restrict__ bk,
                          const float* __restrict__ bv, float* __restrict__ bqkv) {
  int i = blockIdx.x * 256 + threadIdx.x;
  if (i < QKVW) bqkv[i] = (i < D) ? bq[i] : (i < 2 * D) ? bk[i - D] : bv[i - 2 * D];
}

// -------------------- GEMM: C = A @ Bt^T (+epilogue) ---------------------
template <int MODE>
__global__ __launch_bounds__(256) void gemm_bt(const u16* __restrict__ A,
                                               const u16* __restrict__ Bt,
                                               const float* __restrict__ bias,
                                               const float* __restrict__ res,
                                               void* __restrict__ outv,
                                               int M, int Nn, int K) {
  __shared__ __align__(16) u16 As[128 * 32];
  __shared__ __align__(16) u16 Bs[128 * 32];
  const int t = threadIdx.x;
  const int lane = t & 63, w = t >> 6;
  const int wr = w >> 1, wc = w & 1;
  const int lr = lane & 15, lq = lane >> 4;
  const int r0 = blockIdx.y * 128, c0 = blockIdx.x * 128;
  const int rr = t >> 2, cc = (t & 3) * 8;
  f32x4 acc[4][4] = {};
  for (int k0 = 0; k0 < K; k0 += 32) {
    __syncthreads();
    *(s8v*)&As[rr * 32 + cc]        = *(const s8v*)&A[(size_t)(r0 + rr) * K + k0 + cc];
    *(s8v*)&As[(64 + rr) * 32 + cc] = *(const s8v*)&A[(size_t)(r0 + 64 + rr) * K + k0 + cc];
    *(s8v*)&Bs[rr * 32 + cc]        = *(const s8v*)&Bt[(size_t)(c0 + rr) * K + k0 + cc];
    *(s8v*)&Bs[(64 + rr) * 32 + cc] = *(const s8v*)&Bt[(size_t)(c0 + 64 + rr) * K + k0 + cc];
    __syncthreads();
    s8v af[4], bf[4];
#pragma unroll
    for (int m = 0; m < 4; m++) af[m] = *(const s8v*)&As[(wr * 64 + m * 16 + lr) * 32 + lq * 8];
#pragma unroll
    for (int n = 0; n < 4; n++) bf[n] = *(const s8v*)&Bs[(wc * 64 + n * 16 + lr) * 32 + lq * 8];
#pragma unroll
    for (int m = 0; m < 4; m++)
#pragma unroll
      for (int n = 0; n < 4; n++) acc[m][n] = MFMA16(af[m], bf[n], acc[m][n]);
  }
#pragma unroll
  for (int m = 0; m < 4; m++)
#pragma unroll
    for (int n = 0; n < 4; n++) {
      const int col = c0 + wc * 64 + n * 16 + lr;
      const float bcol = bias[col];
#pragma unroll
      for (int j = 0; j < 4; j++) {
        const int row = r0 + wr * 64 + m * 16 + lq * 4 + j;
        float v = acc[m][n][j] + bcol;
        if (MODE == 0) {
          ((u16*)outv)[(size_t)row * Nn + col] = f2bf(v);
        } else if (MODE == 1) {
          v = 0.5f * v * (1.0f + erff(v * 0.70710678118654752f));
          ((u16*)outv)[(size_t)row * Nn + col] = f2bf(v);
        } else {
          ((float*)outv)[(size_t)row * Nn + col] = v + res[(size_t)row * Nn + col];
        }
      }
    }
}

// ----------------------- flash attention + bias --------------------------
// grid: N/16 blocks; block 512 = 8 waves, wave h = head h. m-tile 32.
// All global loads are contiguous-lane b128; LDS swizzled both sides.
__global__ __launch_bounds__(512) void attn_kernel(const u16* __restrict__ qkv,
                                                   const float* __restrict__ bias,
                                                   u16* __restrict__ ctx) {
  extern __shared__ __align__(16) char smem[];
  float* blds = (float*)smem;                   // 16 KB: [16 q][64 swz-chunk of (m,h)]
  u16*   klds = (u16*)(smem + 16384);           // 32 KB: [32 m][512 hd] swz
  u16*   vlds = (u16*)(smem + 16384 + 32768);   // 32 KB: [32 m][512 hd] swz
  u16*   plds = (u16*)(smem + 16384 + 65536);   // 8 KB: per-wave [16 q][32 m]

  const int tid = threadIdx.x, lane = tid & 63, w = tid >> 6, h = w;
  const int lr = lane & 15, lq = lane >> 4;
  const int q0 = blockIdx.x * 16;
  u16* pl = plds + w * 512;

  const u16* qp = qkv + (size_t)(q0 + lr) * QKVW + h * DH + lq * 8;
  s8v qf0 = *(const s8v*)qp;
  s8v qf1 = *(const s8v*)(qp + 32);

  f32x4 cacc[4] = {};
  float mrun[4], lrun[4];
#pragma unroll
  for (int j = 0; j < 4; j++) { mrun[j] = -1e30f; lrun[j] = 0.0f; }

  // swizzle helpers (same involution on writer & reader)
  auto bchunk = [](int c, int q) -> int { return c ^ ((c >> 3) & 7) ^ (((q >> 2) & 3) << 1); };
  auto kvswz  = [](int m) -> int { return (m ^ (m >> 3)) & 7; };

  float4 breg0, breg1;
  int4 kreg[4], vreg[4];

  // ---- prologue: load tile 0 into regs ----
  breg0 = *(const float4*)(bias + (size_t)(q0 + w) * NH + (size_t)lane * 4);
  breg1 = *(const float4*)(bias + (size_t)(q0 + 8 + w) * NH + (size_t)lane * 4);
#pragma unroll
  for (int r = 0; r < 4; r++) {
    const u16* rp = qkv + (size_t)(r * 8 + w) * QKVW;
    kreg[r] = *(const int4*)(rp + D + lane * 8);
    vreg[r] = *(const int4*)(rp + 2 * D + lane * 8);
  }
  // ---- write tile 0 to LDS ----
  {
    int qa = w, qb = 8 + w;
    ((float4*)blds)[qa * 64 + bchunk(lane, qa)] = breg0;
    ((float4*)blds)[qb * 64 + bchunk(lane, qb)] = breg1;
#pragma unroll
    for (int r = 0; r < 4; r++) {
      int m = r * 8 + w; int c = lane ^ kvswz(m);
      ((int4*)(klds + m * 512))[c] = kreg[r];
      ((int4*)(vlds + m * 512))[c] = vreg[r];
    }
  }
  __syncthreads();

  const int NT = N / MT;
  for (int t = 0; t < NT; t++) {
    const int m0 = t * MT;
    const bool pfetch = (t + 1 < NT);
    // ---- issue next-tile global loads (latency hides under compute) ----
    if (pfetch) {
      const int m1 = m0 + MT;
      breg0 = *(const float4*)(bias + (size_t)(q0 + w) * NH + (size_t)m1 * H + lane * 4);
      breg1 = *(const float4*)(bias + (size_t)(q0 + 8 + w) * NH + (size_t)m1 * H + lane * 4);
#pragma unroll
      for (int r = 0; r < 4; r++) {
        const u16* rp = qkv + (size_t)(m1 + r * 8 + w) * QKVW;
        kreg[r] = *(const int4*)(rp + D + lane * 8);
        vreg[r] = *(const int4*)(rp + 2 * D + lane * 8);
      }
    }
    // ---- S = Q K^T (16 q x 32 m) ----
    f32x4 sacc[2] = {};
#pragma unroll
    for (int nb = 0; nb < 2; nb++) {
      const int row = nb * 16 + lr;
      const int s = kvswz(row);
      s8v k0 = *(const s8v*)&klds[row * 512 + (((h * 8 + 0 + lq) ^ s) << 3)];
      s8v k1 = *(const s8v*)&klds[row * 512 + (((h * 8 + 4 + lq) ^ s) << 3)];
      sacc[nb] = MFMA16(qf0, k0, sacc[nb]);
      sacc[nb] = MFMA16(qf1, k1, sacc[nb]);
    }
    // ---- scale + bias (from LDS) + online softmax ----
    float p[2][4];
    float tmax[4] = {-1e30f, -1e30f, -1e30f, -1e30f};
#pragma unroll
    for (int nb = 0; nb < 2; nb++) {
      const int c = (nb * 16 + lr) * 2 + (h >> 2);
      const int cs = c ^ ((c >> 3) & 7) ^ (lq << 1);   // bchunk with (q>>2)&3 == lq
#pragma unroll
      for (int j = 0; j < 4; j++) {
        float sv = sacc[nb][j] * 0.125f + blds[(lq * 4 + j) * 256 + cs * 4 + (h & 3)];
        p[nb][j] = sv;
        tmax[j] = fmaxf(tmax[j], sv);
      }
    }
#pragma unroll
    for (int j = 0; j < 4; j++) {
      tmax[j] = fmaxf(tmax[j], __shfl_xor(tmax[j], 1));
      tmax[j] = fmaxf(tmax[j], __shfl_xor(tmax[j], 2));
      tmax[j] = fmaxf(tmax[j], __shfl_xor(tmax[j], 4));
      tmax[j] = fmaxf(tmax[j], __shfl_xor(tmax[j], 8));
    }
    float scale[4];
#pragma unroll
    for (int j = 0; j < 4; j++) {
      float mnew = fmaxf(mrun[j], tmax[j]);
      scale[j] = __expf(mrun[j] - mnew);
      mrun[j] = mnew;
    }
#pragma unroll
    for (int nb = 0; nb < 2; nb++)
#pragma unroll
      for (int j = 0; j < 4; j++) p[nb][j] = __expf(p[nb][j] - mrun[j]);
#pragma unroll
    for (int j = 0; j < 4; j++) {
      float rs = p[0][j] + p[1][j];
      rs += __shfl_xor(rs, 1);
      rs += __shfl_xor(rs, 2);
      rs += __shfl_xor(rs, 4);
      rs += __shfl_xor(rs, 8);
      lrun[j] = lrun[j] * scale[j] + rs;
    }
#pragma unroll
    for (int db = 0; db < 4; db++)
#pragma unroll
      for (int j = 0; j < 4; j++) cacc[db][j] *= scale[j];
    // ---- P -> per-wave LDS; read back as A-frag ----
#pragma unroll
    for (int nb = 0; nb < 2; nb++)
#pragma unroll
      for (int j = 0; j < 4; j++)
        pl[(lq * 4 + j) * 32 + nb * 16 + lr] = f2bf(p[nb][j]);
    s8v pfr = *(const s8v*)&pl[lr * 32 + lq * 8];
    // ---- ctx += P @ V (V frags via swizzled scalar LDS reads) ----
#pragma unroll
    for (int db = 0; db < 4; db++) {
      s8v vf;
#pragma unroll
      for (int e = 0; e < 8; e++) {
        const int m = lq * 8 + e;
        const int c = (h * 8 + db * 2 + (lr >> 3)) ^ kvswz(m);
        vf[e] = (short)vlds[m * 512 + (c << 3) + (lr & 7)];
      }
      cacc[db] = MFMA16(pfr, vf, cacc[db]);
    }
    // ---- rotate LDS buffer ----
    if (pfetch) {
      __syncthreads();
      {
        int qa = w, qb = 8 + w;
        ((float4*)blds)[qa * 64 + bchunk(lane, qa)] = breg0;
        ((float4*)blds)[qb * 64 + bchunk(lane, qb)] = breg1;
#pragma unroll
        for (int r = 0; r < 4; r++) {
          int m = r * 8 + w; int c = lane ^ kvswz(m);
          ((int4*)(klds + m * 512))[c] = kreg[r];
          ((int4*)(vlds + m * 512))[c] = vreg[r];
        }
      }
      __syncthreads();
    }
  }
  // ---- normalize + write ctx (N,512) bf16 ----
#pragma unroll
  for (int db = 0; db < 4; db++)
#pragma unroll
    for (int j = 0; j < 4; j++) {
      float v = cacc[db][j] / lrun[j];
      ctx[(size_t)(q0 + lq * 4 + j) * D + h * DH + db * 16 + lr] = f2bf(v);
    }
}

// ------------------------------- launch ----------------------------------
extern "C" void kernel_launch(void* const* d_in, const int* in_sizes, int n_in,
                              void* d_out, int out_size, void* d_ws, size_t ws_size,
                              hipStream_t stream) {
  const float* x    = (const float*)d_in[0];
  const float* abias= (const float*)d_in[1];
  const float* ln1g = (const float*)d_in[2];
  const float* ln1b = (const float*)d_in[3];
  const float* wq   = (const float*)d_in[4];
  const float* bq   = (const float*)d_in[5];
  const float* wk   = (const float*)d_in[6];
  const float* bk   = (const float*)d_in[7];
  const float* wv   = (const float*)d_in[8];
  const float* bv   = (const float*)d_in[9];
  const float* wo   = (const float*)d_in[10];
  const float* bo   = (const float*)d_in[11];
  const float* ln2g = (const float*)d_in[12];
  const float* ln2b = (const float*)d_in[13];
  const float* w1   = (const float*)d_in[14];
  const float* b1   = (const float*)d_in[15];
  const float* w2   = (const float*)d_in[16];
  const float* b2   = (const float*)d_in[17];
  float* out = (float*)d_out;

  char* ws = (char*)d_ws;
  size_t off = 0;
  auto alloc = [&](size_t bytes) { size_t o = off; off = (off + bytes + 255) & ~(size_t)255; return (void*)(ws + o); };
  u16*   xn    = (u16*)alloc((size_t)N * D * 2);
  u16*   qkv   = (u16*)alloc((size_t)N * QKVW * 2);
  u16*   ctx   = (u16*)alloc((size_t)N * D * 2);
  float* x2    = (float*)alloc((size_t)N * D * 4);
  u16*   xn2   = (u16*)alloc((size_t)N * D * 2);
  u16*   hb    = (u16*)alloc((size_t)N * F * 2);
  u16*   WqkvT = (u16*)alloc((size_t)QKVW * D * 2);
  u16*   WoT   = (u16*)alloc((size_t)D * D * 2);
  u16*   W1T   = (u16*)alloc((size_t)F * D * 2);
  u16*   W2T   = (u16*)alloc((size_t)D * F * 2);
  float* bqkv  = (float*)alloc((size_t)QKVW * 4);

  // allow 90 KB dynamic LDS for attn (host-side attribute set; graph-safe)
  hipFuncSetAttribute((const void*)attn_kernel,
                      hipFuncAttributeMaxDynamicSharedMemorySize, ATTN_LDS);

  // weight prep (every call: deterministic)
  transpose_w<<<(D * D + 255) / 256, 256, 0, stream>>>(wq, WqkvT, D, D);
  transpose_w<<<(D * D + 255) / 256, 256, 0, stream>>>(wk, WqkvT + D * D, D, D);
  transpose_w<<<(D * D + 255) / 256, 256, 0, stream>>>(wv, WqkvT + 2 * D * D, D, D);
  transpose_w<<<(D * D + 255) / 256, 256, 0, stream>>>(wo, WoT, D, D);
  transpose_w<<<(D * F + 255) / 256, 256, 0, stream>>>(w1, W1T, D, F);
  transpose_w<<<(F * D + 255) / 256, 256, 0, stream>>>(w2, W2T, F, D);
  pack_bqkv<<<(QKVW + 255) / 256, 256, 0, stream>>>(bq, bk, bv, bqkv);

  // LN1
  ln_kernel<<<N / 4, 256, 0, stream>>>(x, ln1g, ln1b, xn);
  // QKV
  gemm_bt<0><<<dim3(QKVW / 128, N / 128), 256, 0, stream>>>(xn, WqkvT, bqkv, nullptr, qkv, N, QKVW, D);
  // attention (coalesced, LDS-staged)
  attn_kernel<<<N / 16, 512, ATTN_LDS, stream>>>(qkv, abias, ctx);
  // O proj + residual -> x2 (fp32)
  gemm_bt<2><<<dim3(D / 128, N / 128), 256, 0, stream>>>(ctx, WoT, bo, x, x2, N, D, D);
  // LN2
  ln_kernel<<<N / 4, 256, 0, stream>>>(x2, ln2g, ln2b, xn2);
  // FFN1 + gelu
  gemm_bt<1><<<dim3(F / 128, N / 128), 256, 0, stream>>>(xn2, W1T, b1, nullptr, hb, N, F, D);
  // FFN2 + residual -> out (fp32)
  gemm_bt<2><<<dim3(D / 128, N / 128), 256, 0, stream>>>(hb, W2T, b2, x2, out, N, D, F);
  (void)in_sizes; (void)n_in; (void)out_size; (void)ws_size;
}

// Round 3
// 399.921 us; speedup vs baseline: 2.9470x; 2.9470x over previous
//
#include <hip/hip_runtime.h>

// Graphormer layer, MI355X round 3: fragment-ordered K/V, bias-only LDS staging,
// swapped-QK flash attention. N=4096, D=512, H=8, DH=64, F=2048.

typedef float f32x4 __attribute__((ext_vector_type(4)));
typedef short s8v  __attribute__((ext_vector_type(8)));   // 8 bf16 in 4 VGPRs
typedef unsigned short u16;

#define MFMA16(a,b,c) __builtin_amdgcn_mfma_f32_16x16x32_bf16((a),(b),(c),0,0,0)

static constexpr int N  = 4096;
static constexpr int D  = 512;
static constexpr int H  = 8;
static constexpr int F  = 2048;
static constexpr int QKVW = 3 * D;       // 1536
static constexpr int NH   = N * H;       // 32768 (bias row stride in floats)
static constexpr int QT   = 16;          // q-rows per attn block
static constexpr int BMT  = 64;          // block m-tile
static constexpr int ATTN_LDS = 65536 + 4096 + 512;   // bias dbuf + mlds + llds

__device__ inline u16 f2bf(float f) {
  union { float f; unsigned u; } x; x.f = f;
  unsigned r = x.u + 0x7fffu + ((x.u >> 16) & 1u);
  return (u16)(r >> 16);
}

typedef const unsigned __attribute__((address_space(1)))* gp_t;
typedef unsigned __attribute__((address_space(3)))* lp_t;
__device__ inline void gl_lds16(const void* g, void* l) {
  __builtin_amdgcn_global_load_lds((gp_t)g, (lp_t)l, 16, 0, 0);
}

// ---------------- LayerNorm: fp32 (N,512) -> bf16 (N,512) ----------------
__global__ __launch_bounds__(256) void ln_kernel(const float* __restrict__ x,
                                                 const float* __restrict__ g,
                                                 const float* __restrict__ b,
                                                 u16* __restrict__ out) {
  const int row  = blockIdx.x * 4 + (threadIdx.x >> 6);
  const int lane = threadIdx.x & 63;
  const float4* xr = (const float4*)(x + (size_t)row * D);
  float4 v0 = xr[lane], v1 = xr[64 + lane];
  float s  = v0.x + v0.y + v0.z + v0.w + v1.x + v1.y + v1.z + v1.w;
  float ss = v0.x*v0.x + v0.y*v0.y + v0.z*v0.z + v0.w*v0.w
           + v1.x*v1.x + v1.y*v1.y + v1.z*v1.z + v1.w*v1.w;
  for (int off = 1; off < 64; off <<= 1) {
    s  += __shfl_xor(s,  off);
    ss += __shfl_xor(ss, off);
  }
  const float mu   = s * (1.0f / D);
  const float var  = ss * (1.0f / D) - mu * mu;
  const float rstd = rsqrtf(var + 1e-5f);
  const float4* g4 = (const float4*)g;
  const float4* b4 = (const float4*)b;
  float4 g0 = g4[lane], g1 = g4[64 + lane];
  float4 b0 = b4[lane], b1 = b4[64 + lane];
  u16* orow = out + (size_t)row * D;
  ushort4 o0, o1;
  o0.x = f2bf((v0.x - mu) * rstd * g0.x + b0.x);
  o0.y = f2bf((v0.y - mu) * rstd * g0.y + b0.y);
  o0.z = f2bf((v0.z - mu) * rstd * g0.z + b0.z);
  o0.w = f2bf((v0.w - mu) * rstd * g0.w + b0.w);
  o1.x = f2bf((v1.x - mu) * rstd * g1.x + b1.x);
  o1.y = f2bf((v1.y - mu) * rstd * g1.y + b1.y);
  o1.z = f2bf((v1.z - mu) * rstd * g1.z + b1.z);
  o1.w = f2bf((v1.w - mu) * rstd * g1.w + b1.w);
  ((ushort4*)orow)[lane]      = o0;
  ((ushort4*)orow)[64 + lane] = o1;
}

// ------------- weight transpose fp32 (R,C) -> bf16 (C,R) ----------------
__global__ void transpose_w(const float* __restrict__ src, u16* __restrict__ dst,
                            int R, int C) {
  int idx = blockIdx.x * 256 + threadIdx.x;
  if (idx < R * C) {
    int r = idx / C, c = idx - r * C;
    dst[(size_t)c * R + r] = f2bf(src[idx]);
  }
}

__global__ void pack_bqkv(const float* __restrict__ bq, const float* __restrict__ bk,
                          const float* __restrict__ bv, float* __restrict__ bqkv) {
  int i = blockIdx.x * 256 + threadIdx.x;
  if (i < QKVW) bqkv[i] = (i < D) ? bq[i] : (i < 2 * D) ? bk[i - D] : bv[i - 2 * D];
}

// ---- K fragment tiles: kt[mt][h][half][lane] (16B chunks), mt = m/16 ----
__global__ void make_ktiles(const u16* __restrict__ qkv, u16* __restrict__ kt) {
  int t = blockIdx.x * 256 + threadIdx.x;        // 262144 chunks
  int ln = t & 63, half = (t >> 6) & 1, h = (t >> 7) & 7, mt = t >> 10;
  int lr = ln & 15, lq = ln >> 4;
  const u16* src = qkv + (size_t)(mt * 16 + lr) * QKVW + D + h * 64 + half * 32 + lq * 8;
  *(int4*)(kt + (size_t)t * 8) = *(const int4*)src;
}

// ---- V^T fragment tiles: vt[mt][h][db][ln<32] : lane(lr,lq) holds
//      V[mt*16 + lq*8+e][h*64+db*16+lr] (only k<16 valid; lanes 32-63 mirror)
__global__ void make_vtiles(const u16* __restrict__ qkv, u16* __restrict__ vt) {
  int t = blockIdx.x * 256 + threadIdx.x;        // 262144 chunks
  int ln = t & 31, db = (t >> 5) & 3, h = (t >> 7) & 7, mt = t >> 10;
  int lr = ln & 15, lq = ln >> 4;
  s8v v;
#pragma unroll
  for (int e = 0; e < 8; e++)
    v[e] = (short)qkv[(size_t)(mt * 16 + lq * 8 + e) * QKVW + 2 * D + h * 64 + db * 16 + lr];
  *(s8v*)(vt + (size_t)t * 8) = v;
}

// -------------------- GEMM: C = A @ Bt^T (+epilogue) ---------------------
template <int MODE>
__global__ __launch_bounds__(256) void gemm_bt(const u16* __restrict__ A,
                                               const u16* __restrict__ Bt,
                                               const float* __restrict__ bias,
                                               const float* __restrict__ res,
                                               void* __restrict__ outv,
                                               int M, int Nn, int K) {
  __shared__ __align__(16) u16 As[128 * 32];
  __shared__ __align__(16) u16 Bs[128 * 32];
  const int t = threadIdx.x;
  const int lane = t & 63, w = t >> 6;
  const int wr = w >> 1, wc = w & 1;
  const int lr = lane & 15, lq = lane >> 4;
  const int r0 = blockIdx.y * 128, c0 = blockIdx.x * 128;
  const int rr = t >> 2, cc = (t & 3) * 8;
  f32x4 acc[4][4] = {};
  for (int k0 = 0; k0 < K; k0 += 32) {
    __syncthreads();
    *(s8v*)&As[rr * 32 + cc]        = *(const s8v*)&A[(size_t)(r0 + rr) * K + k0 + cc];
    *(s8v*)&As[(64 + rr) * 32 + cc] = *(const s8v*)&A[(size_t)(r0 + 64 + rr) * K + k0 + cc];
    *(s8v*)&Bs[rr * 32 + cc]        = *(const s8v*)&Bt[(size_t)(c0 + rr) * K + k0 + cc];
    *(s8v*)&Bs[(64 + rr) * 32 + cc] = *(const s8v*)&Bt[(size_t)(c0 + 64 + rr) * K + k0 + cc];
    __syncthreads();
    s8v af[4], bf[4];
#pragma unroll
    for (int m = 0; m < 4; m++) af[m] = *(const s8v*)&As[(wr * 64 + m * 16 + lr) * 32 + lq * 8];
#pragma unroll
    for (int n = 0; n < 4; n++) bf[n] = *(const s8v*)&Bs[(wc * 64 + n * 16 + lr) * 32 + lq * 8];
#pragma unroll
    for (int m = 0; m < 4; m++)
#pragma unroll
      for (int n = 0; n < 4; n++) acc[m][n] = MFMA16(af[m], bf[n], acc[m][n]);
  }
#pragma unroll
  for (int m = 0; m < 4; m++)
#pragma unroll
    for (int n = 0; n < 4; n++) {
      const int col = c0 + wc * 64 + n * 16 + lr;
      const float bcol = bias[col];
#pragma unroll
      for (int j = 0; j < 4; j++) {
        const int row = r0 + wr * 64 + m * 16 + lq * 4 + j;
        float v = acc[m][n][j] + bcol;
        if (MODE == 0) {
          ((u16*)outv)[(size_t)row * Nn + col] = f2bf(v);
        } else if (MODE == 1) {
          v = 0.5f * v * (1.0f + erff(v * 0.70710678118654752f));
          ((u16*)outv)[(size_t)row * Nn + col] = f2bf(v);
        } else {
          ((float*)outv)[(size_t)row * Nn + col] = v + res[(size_t)row * Nn + col];
        }
      }
    }
}

// ----------------------- flash attention + bias --------------------------
// grid 256 blocks (16 q-rows each), 512 thr = 8 waves = (ms4 in [0,4)) x (hh in [0,2)).
// Swapped QK^T: S^T[m][q]; per-lane softmax keyed by q=lr; wave m-tile 16.
__global__ __launch_bounds__(512) void attn_kernel(const u16* __restrict__ qkv,
                                                   const u16* __restrict__ kt,
                                                   const u16* __restrict__ vt,
                                                   const float* __restrict__ bias,
                                                   u16* __restrict__ ctx) {
  extern __shared__ __align__(16) char smem[];
  float* mlds = (float*)(smem + 65536);          // [8][4][16][2]
  float* llds = (float*)(smem + 65536 + 4096);   // [16 q][8 h] 1/L

  const int tid = threadIdx.x, lane = tid & 63, w = tid >> 6;
  const int lr = lane & 15, lq = lane >> 4;
  const int ms4 = w >> 1, hh = w & 1;
  const int q0 = blockIdx.x * QT;

  // ---- Q fragments (one-time divergent loads) ----
  s8v qf[4][2];
#pragma unroll
  for (int hi = 0; hi < 4; hi++) {
    const u16* qp = qkv + (size_t)(q0 + lr) * QKVW + (hh * 4 + hi) * 64 + lq * 8;
    qf[hi][0] = *(const s8v*)qp;
    qf[hi][1] = *(const s8v*)(qp + 32);
  }

  f32x4 cacc[4][4] = {};
  float mrun[4], lsum[4];
#pragma unroll
  for (int hi = 0; hi < 4; hi++) { mrun[hi] = -1e30f; lsum[hi] = 0.0f; }

  // ---- bias staging helper: wave w stages q-rows {2w, 2w+1} of the tile ----
  // LDS layout: [16 q][128 chunks], chunk slot = c ^ (q&7), c = mrel*2 + hhc.
  auto stage_bias = [&](int buf, int t) {
    char* base = smem + buf * 32768;
#pragma unroll
    for (int k = 0; k < 4; k++) {
      int q = w * 2 + (k >> 1);
      int kk = k & 1;
      int dslot0 = q * 128 + kk * 64;
      int c = (kk * 64 + lane) ^ (q & 7);
      const float* src = bias + (size_t)(q0 + q) * NH + (size_t)(t * BMT + (c >> 1)) * H + (c & 1) * 4;
      gl_lds16(src, base + (size_t)dslot0 * 16);
    }
  };

  stage_bias(0, 0);
  __syncthreads();

  const int NT = N / BMT;   // 64
  int cur = 0;
  for (int t = 0; t < NT; t++) {
    if (t + 1 < NT) stage_bias(cur ^ 1, t + 1);
    const float* bb = (const float*)(smem + cur * 32768);
    const int mt = t * 4 + ms4;                      // global m/16 tile

    // bias quads: bq4[j] = bias[q=lr][mrel = ms4*16+lq*4+j][hh*4 .. +4]
    float4 bq4[4];
#pragma unroll
    for (int j = 0; j < 4; j++) {
      int c = (ms4 * 16 + lq * 4 + j) * 2 + hh;
      int slot = c ^ (lr & 7);
      bq4[j] = ((const float4*)bb)[lr * 128 + slot];
    }

#pragma unroll
    for (int hi = 0; hi < 4; hi++) {
      const int h = hh * 4 + hi;
      // K fragments (coalesced b128 from ktiles)
      const u16* kp = kt + ((size_t)(mt * 8 + h) * 2) * 512 + lane * 8;
      s8v kf0 = *(const s8v*)kp;
      s8v kf1 = *(const s8v*)(kp + 512);
      f32x4 sacc = {};
      sacc = MFMA16(kf0, qf[hi][0], sacc);
      sacc = MFMA16(kf1, qf[hi][1], sacc);
      // scale + bias
      float p4[4];
      float tmax = -1e30f;
#pragma unroll
      for (int j = 0; j < 4; j++) {
        float sv = sacc[j] * 0.125f + ((hi == 0) ? bq4[j].x : (hi == 1) ? bq4[j].y
                   : (hi == 2) ? bq4[j].z : bq4[j].w);
        p4[j] = sv;
        tmax = fmaxf(tmax, sv);
      }
      tmax = fmaxf(tmax, __shfl_xor(tmax, 16));
      tmax = fmaxf(tmax, __shfl_xor(tmax, 32));
      float mnew = fmaxf(mrun[hi], tmax);
      float sc = __expf(mrun[hi] - mnew);
      mrun[hi] = mnew;
      float psum = 0.0f;
#pragma unroll
      for (int j = 0; j < 4; j++) { p4[j] = __expf(p4[j] - mnew); psum += p4[j]; }
      lsum[hi] = lsum[hi] * sc + psum;
#pragma unroll
      for (int db = 0; db < 4; db++)
#pragma unroll
        for (int j = 0; j < 4; j++) cacc[hi][db][j] *= sc;
      // pack P to bf16 pairs and redistribute to B-frag layout
      unsigned u0, u1;
      asm("v_cvt_pk_bf16_f32 %0, %1, %2" : "=v"(u0) : "v"(p4[0]), "v"(p4[1]));
      asm("v_cvt_pk_bf16_f32 %0, %1, %2" : "=v"(u1) : "v"(p4[2]), "v"(p4[3]));
      unsigned pb[4];
#pragma unroll
      for (int r = 0; r < 4; r++) {
        int lqp = (2 * lq + (r >> 1)) & 3;
        unsigned g = (unsigned)__shfl((int)((r & 1) ? u1 : u0), lr | (lqp << 4));
        pb[r] = (lq < 2) ? g : 0u;
      }
      union { unsigned u[4]; s8v v; } pa;
      pa.u[0] = pb[0]; pa.u[1] = pb[1]; pa.u[2] = pb[2]; pa.u[3] = pb[3];
      // PV: cacc += V^T-frag x P  (k=16 effective)
      const u16* vp = vt + ((size_t)(mt * 8 + h) * 4) * 256 + (lane & 31) * 8;
#pragma unroll
      for (int db = 0; db < 4; db++) {
        s8v vf = *(const s8v*)(vp + (size_t)db * 256);
        cacc[hi][db] = MFMA16(vf, pa.v, cacc[hi][db]);
      }
    }
    __syncthreads();
    cur ^= 1;
  }

  // ---- merge: reduce lsum across lq; publish (m,l); combine across ms4 ----
#pragma unroll
  for (int hi = 0; hi < 4; hi++) {
    lsum[hi] += __shfl_xor(lsum[hi], 16);
    lsum[hi] += __shfl_xor(lsum[hi], 32);
  }
  if (lq == 0) {
#pragma unroll
    for (int hi = 0; hi < 4; hi++) {
      mlds[((w * 4 + hi) * 16 + lr) * 2]     = mrun[hi];
      mlds[((w * 4 + hi) * 16 + lr) * 2 + 1] = lsum[hi];
    }
  }
  __syncthreads();
  float fac[4];
#pragma unroll
  for (int hi = 0; hi < 4; hi++) {
    float ms_[4], ls_[4];
    float M = -1e30f;
#pragma unroll
    for (int s = 0; s < 4; s++) {
      int pw = s * 2 + hh;
      ms_[s] = mlds[((pw * 4 + hi) * 16 + lr) * 2];
      ls_[s] = mlds[((pw * 4 + hi) * 16 + lr) * 2 + 1];
      M = fmaxf(M, ms_[s]);
    }
    float L = 0.0f;
#pragma unroll
    for (int s = 0; s < 4; s++) L += ls_[s] * __expf(ms_[s] - M);
    fac[hi] = __expf(mrun[hi] - M);
    if (lq == 0 && ms4 == 0) llds[lr * 8 + hh * 4 + hi] = 1.0f / L;
  }
  // accumulate scaled partials into ctxT (f32 [512 d][16 q]) in smem
  float* ctxT = (float*)smem;
#pragma unroll 1
  for (int s = 0; s < 4; s++) {
    if (ms4 == s) {
#pragma unroll
      for (int hi = 0; hi < 4; hi++)
#pragma unroll
        for (int db = 0; db < 4; db++)
#pragma unroll
          for (int j = 0; j < 4; j++) {
            int d = (hh * 4 + hi) * 64 + db * 16 + lq * 4 + j;
            int idx = d * 16 + lr;
            float v = cacc[hi][db][j] * fac[hi];
            ctxT[idx] = (s == 0) ? v : (ctxT[idx] + v);
          }
    }
    __syncthreads();
  }
  // write ctx (16 q x 512 d, bf16, coalesced 32B per thread)
  {
    int q = tid >> 5, d0 = (tid & 31) * 16;
    float lr8[8];
    u16 tmp[16];
#pragma unroll
    for (int i = 0; i < 16; i++) {
      float v = ctxT[(d0 + i) * 16 + q] * llds[q * 8 + ((d0 + i) >> 6)];
      tmp[i] = f2bf(v);
    }
    (void)lr8;
    u16* op = ctx + (size_t)(q0 + q) * D + d0;
    *(int4*)op       = *(int4*)&tmp[0];
    *(int4*)(op + 8) = *(int4*)&tmp[8];
  }
}

// ------------------------------- launch ----------------------------------
extern "C" void kernel_launch(void* const* d_in, const int* in_sizes, int n_in,
                              void* d_out, int out_size, void* d_ws, size_t ws_size,
                              hipStream_t stream) {
  const float* x    = (const float*)d_in[0];
  const float* abias= (const float*)d_in[1];
  const float* ln1g = (const float*)d_in[2];
  const float* ln1b = (const float*)d_in[3];
  const float* wq   = (const float*)d_in[4];
  const float* bq   = (const float*)d_in[5];
  const float* wk   = (const float*)d_in[6];
  const float* bk   = (const float*)d_in[7];
  const float* wv   = (const float*)d_in[8];
  const float* bv   = (const float*)d_in[9];
  const float* wo   = (const float*)d_in[10];
  const float* bo   = (const float*)d_in[11];
  const float* ln2g = (const float*)d_in[12];
  const float* ln2b = (const float*)d_in[13];
  const float* w1   = (const float*)d_in[14];
  const float* b1   = (const float*)d_in[15];
  const float* w2   = (const float*)d_in[16];
  const float* b2   = (const float*)d_in[17];
  float* out = (float*)d_out;

  char* ws = (char*)d_ws;
  size_t off = 0;
  auto alloc = [&](size_t bytes) { size_t o = off; off = (off + bytes + 255) & ~(size_t)255; return (void*)(ws + o); };
  u16*   xn    = (u16*)alloc((size_t)N * D * 2);
  u16*   qkv   = (u16*)alloc((size_t)N * QKVW * 2);
  u16*   ktl   = (u16*)alloc((size_t)N * D * 2);
  u16*   vtl   = (u16*)alloc((size_t)N * D * 2);
  u16*   ctx   = (u16*)alloc((size_t)N * D * 2);
  float* x2    = (float*)alloc((size_t)N * D * 4);
  u16*   xn2   = (u16*)alloc((size_t)N * D * 2);
  u16*   hb    = (u16*)alloc((size_t)N * F * 2);
  u16*   WqkvT = (u16*)alloc((size_t)QKVW * D * 2);
  u16*   WoT   = (u16*)alloc((size_t)D * D * 2);
  u16*   W1T   = (u16*)alloc((size_t)F * D * 2);
  u16*   W2T   = (u16*)alloc((size_t)D * F * 2);
  float* bqkv  = (float*)alloc((size_t)QKVW * 4);

  hipFuncSetAttribute((const void*)attn_kernel,
                      hipFuncAttributeMaxDynamicSharedMemorySize, ATTN_LDS);

  // weight prep
  transpose_w<<<(D * D + 255) / 256, 256, 0, stream>>>(wq, WqkvT, D, D);
  transpose_w<<<(D * D + 255) / 256, 256, 0, stream>>>(wk, WqkvT + D * D, D, D);
  transpose_w<<<(D * D + 255) / 256, 256, 0, stream>>>(wv, WqkvT + 2 * D * D, D, D);
  transpose_w<<<(D * D + 255) / 256, 256, 0, stream>>>(wo, WoT, D, D);
  transpose_w<<<(D * F + 255) / 256, 256, 0, stream>>>(w1, W1T, D, F);
  transpose_w<<<(F * D + 255) / 256, 256, 0, stream>>>(w2, W2T, F, D);
  pack_bqkv<<<(QKVW + 255) / 256, 256, 0, stream>>>(bq, bk, bv, bqkv);

  // LN1 -> QKV
  ln_kernel<<<N / 4, 256, 0, stream>>>(x, ln1g, ln1b, xn);
  gemm_bt<0><<<dim3(QKVW / 128, N / 128), 256, 0, stream>>>(xn, WqkvT, bqkv, nullptr, qkv, N, QKVW, D);
  // K/V fragment tiles
  make_ktiles<<<1024, 256, 0, stream>>>(qkv, ktl);
  make_vtiles<<<1024, 256, 0, stream>>>(qkv, vtl);
  // attention
  attn_kernel<<<N / QT, 512, ATTN_LDS, stream>>>(qkv, ktl, vtl, abias, ctx);
  // O proj + residual -> x2 (fp32)
  gemm_bt<2><<<dim3(D / 128, N / 128), 256, 0, stream>>>(ctx, WoT, bo, x, x2, N, D, D);
  // LN2 -> FFN
  ln_kernel<<<N / 4, 256, 0, stream>>>(x2, ln2g, ln2b, xn2);
  gemm_bt<1><<<dim3(F / 128, N / 128), 256, 0, stream>>>(xn2, W1T, b1, nullptr, hb, N, F, D);
  gemm_bt<2><<<dim3(D / 128, N / 128), 256, 0, stream>>>(hb, W2T, b2, x2, out, N, D, F);
  (void)in_sizes; (void)n_in; (void)out_size; (void)ws_size;
}

// Round 4
// 356.384 us; speedup vs baseline: 3.3070x; 1.1222x over previous
//
#include <hip/hip_runtime.h>

// Graphormer layer, MI355X round 4: QT=64 + m-split-4 attention (K/V traffic /4),
// transposed swizzled bias LDS, reg-staged T14 pipeline, flash partial merge.
// N=4096, D=512, H=8, DH=64, F=2048. fp32 in/out, bf16 MFMA internally.

typedef float f32x4 __attribute__((ext_vector_type(4)));
typedef short s8v  __attribute__((ext_vector_type(8)));   // 8 bf16 in 4 VGPRs
typedef unsigned short u16;

#define MFMA16(a,b,c) __builtin_amdgcn_mfma_f32_16x16x32_bf16((a),(b),(c),0,0,0)

static constexpr int N  = 4096;
static constexpr int D  = 512;
static constexpr int H  = 8;
static constexpr int F  = 2048;
static constexpr int QKVW = 3 * D;       // 1536
static constexpr int NH   = N * H;       // 32768 (bias row stride in floats)
static constexpr int QT   = 64;          // q-rows per attn block
static constexpr int MS   = 4;           // m-splits
static constexpr int ATTN_LDS = 65536;   // bias double buffer 2 x 32 KB

__device__ inline u16 f2bf(float f) {
  union { float f; unsigned u; } x; x.f = f;
  unsigned r = x.u + 0x7fffu + ((x.u >> 16) & 1u);
  return (u16)(r >> 16);
}

// ---------------- LayerNorm: fp32 (N,512) -> bf16 (N,512) ----------------
__global__ __launch_bounds__(256) void ln_kernel(const float* __restrict__ x,
                                                 const float* __restrict__ g,
                                                 const float* __restrict__ b,
                                                 u16* __restrict__ out) {
  const int row  = blockIdx.x * 4 + (threadIdx.x >> 6);
  const int lane = threadIdx.x & 63;
  const float4* xr = (const float4*)(x + (size_t)row * D);
  float4 v0 = xr[lane], v1 = xr[64 + lane];
  float s  = v0.x + v0.y + v0.z + v0.w + v1.x + v1.y + v1.z + v1.w;
  float ss = v0.x*v0.x + v0.y*v0.y + v0.z*v0.z + v0.w*v0.w
           + v1.x*v1.x + v1.y*v1.y + v1.z*v1.z + v1.w*v1.w;
  for (int off = 1; off < 64; off <<= 1) {
    s  += __shfl_xor(s,  off);
    ss += __shfl_xor(ss, off);
  }
  const float mu   = s * (1.0f / D);
  const float var  = ss * (1.0f / D) - mu * mu;
  const float rstd = rsqrtf(var + 1e-5f);
  const float4* g4 = (const float4*)g;
  const float4* b4 = (const float4*)b;
  float4 g0 = g4[lane], g1 = g4[64 + lane];
  float4 b0 = b4[lane], b1 = b4[64 + lane];
  u16* orow = out + (size_t)row * D;
  ushort4 o0, o1;
  o0.x = f2bf((v0.x - mu) * rstd * g0.x + b0.x);
  o0.y = f2bf((v0.y - mu) * rstd * g0.y + b0.y);
  o0.z = f2bf((v0.z - mu) * rstd * g0.z + b0.z);
  o0.w = f2bf((v0.w - mu) * rstd * g0.w + b0.w);
  o1.x = f2bf((v1.x - mu) * rstd * g1.x + b1.x);
  o1.y = f2bf((v1.y - mu) * rstd * g1.y + b1.y);
  o1.z = f2bf((v1.z - mu) * rstd * g1.z + b1.z);
  o1.w = f2bf((v1.w - mu) * rstd * g1.w + b1.w);
  ((ushort4*)orow)[lane]      = o0;
  ((ushort4*)orow)[64 + lane] = o1;
}

// ------------- weight transpose fp32 (R,C) -> bf16 (C,R) ----------------
__global__ void transpose_w(const float* __restrict__ src, u16* __restrict__ dst,
                            int R, int C) {
  int idx = blockIdx.x * 256 + threadIdx.x;
  if (idx < R * C) {
    int r = idx / C, c = idx - r * C;
    dst[(size_t)c * R + r] = f2bf(src[idx]);
  }
}

__global__ void pack_bqkv(const float* __restrict__ bq, const float* __restrict__ bk,
                          const float* __restrict__ bv, float* __restrict__ bqkv) {
  int i = blockIdx.x * 256 + threadIdx.x;
  if (i < QKVW) bqkv[i] = (i < D) ? bq[i] : (i < 2 * D) ? bk[i - D] : bv[i - 2 * D];
}

// ---- K fragment tiles: kt[mt][h][half][lane] (16B chunks), mt = m/16 ----
__global__ void make_ktiles(const u16* __restrict__ qkv, u16* __restrict__ kt) {
  int t = blockIdx.x * 256 + threadIdx.x;        // 262144 chunks
  int ln = t & 63, half = (t >> 6) & 1, h = (t >> 7) & 7, mt = t >> 10;
  int lr = ln & 15, lq = ln >> 4;
  const u16* src = qkv + (size_t)(mt * 16 + lr) * QKVW + D + h * 64 + half * 32 + lq * 8;
  *(int4*)(kt + (size_t)t * 8) = *(const int4*)src;
}

// ---- V^T fragment tiles: vt[mt][h][db][ln<32] ----
__global__ void make_vtiles(const u16* __restrict__ qkv, u16* __restrict__ vt) {
  int t = blockIdx.x * 256 + threadIdx.x;        // 262144 chunks
  int ln = t & 31, db = (t >> 5) & 3, h = (t >> 7) & 7, mt = t >> 10;
  int lr = ln & 15, lq = ln >> 4;
  s8v v;
#pragma unroll
  for (int e = 0; e < 8; e++)
    v[e] = (short)qkv[(size_t)(mt * 16 + lq * 8 + e) * QKVW + 2 * D + h * 64 + db * 16 + lr];
  *(s8v*)(vt + (size_t)t * 8) = v;
}

// -------------------- GEMM: C = A @ Bt^T (+epilogue) ---------------------
template <int MODE>
__global__ __launch_bounds__(256) void gemm_bt(const u16* __restrict__ A,
                                               const u16* __restrict__ Bt,
                                               const float* __restrict__ bias,
                                               const float* __restrict__ res,
                                               void* __restrict__ outv,
                                               int M, int Nn, int K) {
  __shared__ __align__(16) u16 As[128 * 32];
  __shared__ __align__(16) u16 Bs[128 * 32];
  const int t = threadIdx.x;
  const int lane = t & 63, w = t >> 6;
  const int wr = w >> 1, wc = w & 1;
  const int lr = lane & 15, lq = lane >> 4;
  const int r0 = blockIdx.y * 128, c0 = blockIdx.x * 128;
  const int rr = t >> 2, cc = (t & 3) * 8;
  f32x4 acc[4][4] = {};
  for (int k0 = 0; k0 < K; k0 += 32) {
    __syncthreads();
    *(s8v*)&As[rr * 32 + cc]        = *(const s8v*)&A[(size_t)(r0 + rr) * K + k0 + cc];
    *(s8v*)&As[(64 + rr) * 32 + cc] = *(const s8v*)&A[(size_t)(r0 + 64 + rr) * K + k0 + cc];
    *(s8v*)&Bs[rr * 32 + cc]        = *(const s8v*)&Bt[(size_t)(c0 + rr) * K + k0 + cc];
    *(s8v*)&Bs[(64 + rr) * 32 + cc] = *(const s8v*)&Bt[(size_t)(c0 + 64 + rr) * K + k0 + cc];
    __syncthreads();
    s8v af[4], bf[4];
#pragma unroll
    for (int m = 0; m < 4; m++) af[m] = *(const s8v*)&As[(wr * 64 + m * 16 + lr) * 32 + lq * 8];
#pragma unroll
    for (int n = 0; n < 4; n++) bf[n] = *(const s8v*)&Bs[(wc * 64 + n * 16 + lr) * 32 + lq * 8];
#pragma unroll
    for (int m = 0; m < 4; m++)
#pragma unroll
      for (int n = 0; n < 4; n++) acc[m][n] = MFMA16(af[m], bf[n], acc[m][n]);
  }
#pragma unroll
  for (int m = 0; m < 4; m++)
#pragma unroll
    for (int n = 0; n < 4; n++) {
      const int col = c0 + wc * 64 + n * 16 + lr;
      const float bcol = bias[col];
#pragma unroll
      for (int j = 0; j < 4; j++) {
        const int row = r0 + wr * 64 + m * 16 + lq * 4 + j;
        float v = acc[m][n][j] + bcol;
        if (MODE == 0) {
          ((u16*)outv)[(size_t)row * Nn + col] = f2bf(v);
        } else if (MODE == 1) {
          v = 0.5f * v * (1.0f + erff(v * 0.70710678118654752f));
          ((u16*)outv)[(size_t)row * Nn + col] = f2bf(v);
        } else {
          ((float*)outv)[(size_t)row * Nn + col] = v + res[(size_t)row * Nn + col];
        }
      }
    }
}

// ----------------------- flash attention + bias --------------------------
// grid 256 = (qb 64) x (ms 4). block 512 thr = 8 waves; wave w = head.
// Per block: 64 q-rows, m-range [ms*1024, +1024) in 64 tiles of 16.
// Writes unnormalized partials + (m,l); attn_merge combines the 4 splits.
__global__ __launch_bounds__(512, 2) void attn_kernel(const u16* __restrict__ qkv,
                                                      const u16* __restrict__ kt,
                                                      const u16* __restrict__ vt,
                                                      const float* __restrict__ bias,
                                                      float* __restrict__ ctxp,
                                                      float* __restrict__ ml) {
  extern __shared__ __align__(16) char smem[];
  const int tid = threadIdx.x, lane = tid & 63, w = tid >> 6;  // w = head
  const int lr = lane & 15, lq = lane >> 4;
  const int qb = blockIdx.x >> 2, ms = blockIdx.x & 3;
  const int q0 = qb * QT;
  const int mt0 = ms * 64;                    // base m-tile index (units of 16)

  // ---- Q fragments: qf[qc][half] (one-time loads) ----
  s8v qf[4][2];
#pragma unroll
  for (int qc = 0; qc < 4; qc++) {
    const u16* qp = qkv + (size_t)(q0 + qc * 16 + lr) * QKVW + w * 64 + lq * 8;
    qf[qc][0] = *(const s8v*)qp;
    qf[qc][1] = *(const s8v*)(qp + 32);
  }

  f32x4 cacc[4][4] = {};                       // [qc][db]
  float mrun[4], lsum[4];
#pragma unroll
  for (int qc = 0; qc < 4; qc++) { mrun[qc] = -1e30f; lsum[qc] = 0.0f; }

  // ---- bias staging: regs -> LDS [h=8][q=64][m=16] f32, chunk-swizzled ----
  f32x4 breg[4];
  auto load_bias = [&](int t) {
#pragma unroll
    for (int c4 = 0; c4 < 4; c4++) {
      int g = c4 * 512 + tid;
      int q = g >> 5, m = (g >> 1) & 15, h0 = (g & 1) * 4;
      breg[c4] = *(const f32x4*)(bias + (size_t)(q0 + q) * NH
                                 + (size_t)((mt0 + t) * 16 + m) * H + h0);
    }
  };
  auto write_bias = [&](int buf) {
    float* bl = (float*)(smem + buf * 32768);
#pragma unroll
    for (int c4 = 0; c4 < 4; c4++) {
      int g = c4 * 512 + tid;
      int q = g >> 5, m = (g >> 1) & 15, h0 = (g & 1) * 4;
      int slot = (m >> 2) ^ (q & 3);
#pragma unroll
      for (int e = 0; e < 4; e++)
        bl[(h0 + e) * 1024 + q * 16 + slot * 4 + (m & 3)] = breg[c4][e];
    }
  };

  // ---- prologue: tile 0 bias + K ----
  load_bias(0);
  write_bias(0);
  s8v kc0, kc1;
  {
    const u16* kp = kt + ((size_t)(mt0 * 8 + w) * 2) * 512 + lane * 8;
    kc0 = *(const s8v*)kp;
    kc1 = *(const s8v*)(kp + 512);
  }
  __syncthreads();

  int cur = 0;
  for (int t = 0; t < 64; t++) {
    const int mt = mt0 + t;
    const bool pf = (t + 1 < 64);
    // prefetch next tile: bias (regs) + K (regs)
    if (pf) load_bias(t + 1);
    s8v kn0 = kc0, kn1 = kc1;
    if (pf) {
      const u16* kp = kt + ((size_t)((mt + 1) * 8 + w) * 2) * 512 + lane * 8;
      kn0 = *(const s8v*)kp;
      kn1 = *(const s8v*)(kp + 512);
    }
    // ---- QK^T: S^T[m 16][q 64] ----
    f32x4 sacc[4] = {};
#pragma unroll
    for (int qc = 0; qc < 4; qc++) {
      sacc[qc] = MFMA16(kc0, qf[qc][0], sacc[qc]);
      sacc[qc] = MFMA16(kc1, qf[qc][1], sacc[qc]);
    }
    // ---- V fragments (issue early; used after softmax) ----
    s8v vf[4];
    const u16* vp = vt + ((size_t)(mt * 8 + w) * 4) * 256 + (lane & 31) * 8;
#pragma unroll
    for (int db = 0; db < 4; db++) vf[db] = *(const s8v*)(vp + (size_t)db * 256);

    const float* bl = (const float*)(smem + cur * 32768);
#pragma unroll
    for (int qc = 0; qc < 4; qc++) {
      const int q = qc * 16 + lr;
      f32x4 b4 = *(const f32x4*)(bl + w * 1024 + q * 16 + (lq ^ (q & 3)) * 4);
      float p4[4];
      float tmax = -1e30f;
#pragma unroll
      for (int j = 0; j < 4; j++) {
        float sv = sacc[qc][j] * 0.125f + b4[j];
        p4[j] = sv;
        tmax = fmaxf(tmax, sv);
      }
      tmax = fmaxf(tmax, __shfl_xor(tmax, 16));
      tmax = fmaxf(tmax, __shfl_xor(tmax, 32));
      if (!__all(tmax <= mrun[qc])) {          // T13: skip no-op rescale
        float mnew = fmaxf(mrun[qc], tmax);
        float sc = __expf(mrun[qc] - mnew);
        mrun[qc] = mnew;
        lsum[qc] *= sc;
#pragma unroll
        for (int db = 0; db < 4; db++) cacc[qc][db] *= sc;
      }
      float psum = 0.0f;
#pragma unroll
      for (int j = 0; j < 4; j++) { p4[j] = __expf(p4[j] - mrun[qc]); psum += p4[j]; }
      lsum[qc] += psum;
      // pack P -> bf16 B-fragment (k = m, 16 effective of 32)
      unsigned u0, u1;
      asm("v_cvt_pk_bf16_f32 %0, %1, %2" : "=v"(u0) : "v"(p4[0]), "v"(p4[1]));
      asm("v_cvt_pk_bf16_f32 %0, %1, %2" : "=v"(u1) : "v"(p4[2]), "v"(p4[3]));
      union { unsigned u[4]; s8v v; } pa;
#pragma unroll
      for (int r = 0; r < 4; r++) {
        int lqp = (2 * lq + (r >> 1)) & 3;
        unsigned g = (unsigned)__shfl((int)((r & 1) ? u1 : u0), lr | (lqp << 4));
        pa.u[r] = (lq < 2) ? g : 0u;
      }
#pragma unroll
      for (int db = 0; db < 4; db++) cacc[qc][db] = MFMA16(vf[db], pa.v, cacc[qc][db]);
    }
    // rotate: write next bias tile, single barrier
    if (pf) write_bias(cur ^ 1);
    __syncthreads();
    kc0 = kn0; kc1 = kn1;
    cur ^= 1;
  }

  // ---- finalize: reduce lsum over lq; write partials ----
#pragma unroll
  for (int qc = 0; qc < 4; qc++) {
    lsum[qc] += __shfl_xor(lsum[qc], 16);
    lsum[qc] += __shfl_xor(lsum[qc], 32);
  }
  if (lq == 0) {
#pragma unroll
    for (int qc = 0; qc < 4; qc++) {
      float2 v = make_float2(mrun[qc], lsum[qc]);
      *(float2*)(ml + (((size_t)ms * N + q0 + qc * 16 + lr) * H + w) * 2) = v;
    }
  }
#pragma unroll
  for (int qc = 0; qc < 4; qc++)
#pragma unroll
    for (int db = 0; db < 4; db++) {
      const size_t q = q0 + qc * 16 + lr;
      *(f32x4*)(ctxp + ((size_t)ms * N + q) * D + w * 64 + db * 16 + lq * 4)
          = cacc[qc][db];
    }
}

// ---- merge the 4 m-split partials -> ctx bf16 (N,512) ----
__global__ __launch_bounds__(256) void attn_merge(const float* __restrict__ ctxp,
                                                  const float* __restrict__ ml,
                                                  u16* __restrict__ ctx) {
  int idx = blockIdx.x * 256 + threadIdx.x;     // N * 128
  int q = idx >> 7, c = idx & 127;
  int d0 = c * 4, h = c >> 4;
  float m_[MS], l_[MS], M = -1e30f;
#pragma unroll
  for (int s = 0; s < MS; s++) {
    float2 v = *(const float2*)(ml + (((size_t)s * N + q) * H + h) * 2);
    m_[s] = v.x; l_[s] = v.y;
    M = fmaxf(M, v.x);
  }
  float L = 0.0f, w_[MS];
#pragma unroll
  for (int s = 0; s < MS; s++) { w_[s] = __expf(m_[s] - M); L += l_[s] * w_[s]; }
  const float inv = 1.0f / L;
  f32x4 o = {0.0f, 0.0f, 0.0f, 0.0f};
#pragma unroll
  for (int s = 0; s < MS; s++) {
    f32x4 p = *(const f32x4*)(ctxp + ((size_t)s * N + q) * D + d0);
#pragma unroll
    for (int j = 0; j < 4; j++) o[j] += p[j] * w_[s];
  }
  ushort4 r;
  r.x = f2bf(o[0] * inv); r.y = f2bf(o[1] * inv);
  r.z = f2bf(o[2] * inv); r.w = f2bf(o[3] * inv);
  *(ushort4*)(ctx + (size_t)q * D + d0) = r;
}

// ------------------------------- launch ----------------------------------
extern "C" void kernel_launch(void* const* d_in, const int* in_sizes, int n_in,
                              void* d_out, int out_size, void* d_ws, size_t ws_size,
                              hipStream_t stream) {
  const float* x    = (const float*)d_in[0];
  const float* abias= (const float*)d_in[1];
  const float* ln1g = (const float*)d_in[2];
  const float* ln1b = (const float*)d_in[3];
  const float* wq   = (const float*)d_in[4];
  const float* bq   = (const float*)d_in[5];
  const float* wk   = (const float*)d_in[6];
  const float* bk   = (const float*)d_in[7];
  const float* wv   = (const float*)d_in[8];
  const float* bv   = (const float*)d_in[9];
  const float* wo   = (const float*)d_in[10];
  const float* bo   = (const float*)d_in[11];
  const float* ln2g = (const float*)d_in[12];
  const float* ln2b = (const float*)d_in[13];
  const float* w1   = (const float*)d_in[14];
  const float* b1   = (const float*)d_in[15];
  const float* w2   = (const float*)d_in[16];
  const float* b2   = (const float*)d_in[17];
  float* out = (float*)d_out;

  char* ws = (char*)d_ws;
  size_t off = 0;
  auto alloc = [&](size_t bytes) { size_t o = off; off = (off + bytes + 255) & ~(size_t)255; return (void*)(ws + o); };
  u16*   xn    = (u16*)alloc((size_t)N * D * 2);
  u16*   qkv   = (u16*)alloc((size_t)N * QKVW * 2);
  u16*   ktl   = (u16*)alloc((size_t)N * D * 2);
  u16*   vtl   = (u16*)alloc((size_t)N * D * 2);
  u16*   ctx   = (u16*)alloc((size_t)N * D * 2);
  float* x2    = (float*)alloc((size_t)N * D * 4);
  u16*   xn2   = (u16*)alloc((size_t)N * D * 2);
  u16*   hb    = (u16*)alloc((size_t)N * F * 2);
  u16*   WqkvT = (u16*)alloc((size_t)QKVW * D * 2);
  u16*   WoT   = (u16*)alloc((size_t)D * D * 2);
  u16*   W1T   = (u16*)alloc((size_t)F * D * 2);
  u16*   W2T   = (u16*)alloc((size_t)D * F * 2);
  float* bqkv  = (float*)alloc((size_t)QKVW * 4);
  float* ctxp  = (float*)alloc((size_t)MS * N * D * 4);   // 32 MB partials
  float* ml    = (float*)alloc((size_t)MS * N * H * 2 * 4);

  hipFuncSetAttribute((const void*)attn_kernel,
                      hipFuncAttributeMaxDynamicSharedMemorySize, ATTN_LDS);

  // weight prep
  transpose_w<<<(D * D + 255) / 256, 256, 0, stream>>>(wq, WqkvT, D, D);
  transpose_w<<<(D * D + 255) / 256, 256, 0, stream>>>(wk, WqkvT + D * D, D, D);
  transpose_w<<<(D * D + 255) / 256, 256, 0, stream>>>(wv, WqkvT + 2 * D * D, D, D);
  transpose_w<<<(D * D + 255) / 256, 256, 0, stream>>>(wo, WoT, D, D);
  transpose_w<<<(D * F + 255) / 256, 256, 0, stream>>>(w1, W1T, D, F);
  transpose_w<<<(F * D + 255) / 256, 256, 0, stream>>>(w2, W2T, F, D);
  pack_bqkv<<<(QKVW + 255) / 256, 256, 0, stream>>>(bq, bk, bv, bqkv);

  // LN1 -> QKV
  ln_kernel<<<N / 4, 256, 0, stream>>>(x, ln1g, ln1b, xn);
  gemm_bt<0><<<dim3(QKVW / 128, N / 128), 256, 0, stream>>>(xn, WqkvT, bqkv, nullptr, qkv, N, QKVW, D);
  // K/V fragment tiles
  make_ktiles<<<1024, 256, 0, stream>>>(qkv, ktl);
  make_vtiles<<<1024, 256, 0, stream>>>(qkv, vtl);
  // attention: 256 blocks = 64 q-blocks x 4 m-splits, then merge
  attn_kernel<<<(N / QT) * MS, 512, ATTN_LDS, stream>>>(qkv, ktl, vtl, abias, ctxp, ml);
  attn_merge<<<(N * 128) / 256, 256, 0, stream>>>(ctxp, ml, ctx);
  // O proj + residual -> x2 (fp32)
  gemm_bt<2><<<dim3(D / 128, N / 128), 256, 0, stream>>>(ctx, WoT, bo, x, x2, N, D, D);
  // LN2 -> FFN
  ln_kernel<<<N / 4, 256, 0, stream>>>(x2, ln2g, ln2b, xn2);
  gemm_bt<1><<<dim3(F / 128, N / 128), 256, 0, stream>>>(xn2, W1T, b1, nullptr, hb, N, F, D);
  gemm_bt<2><<<dim3(D / 128, N / 128), 256, 0, stream>>>(hb, W2T, b2, x2, out, N, D, F);
  (void)in_sizes; (void)n_in; (void)out_size; (void)ws_size;
}

// Round 6
// 348.460 us; speedup vs baseline: 3.3822x; 1.0227x over previous
//
#include <hip/hip_runtime.h>

// Graphormer layer, MI355X round 6: round-4 base (known-good GEMM/transpose)
// + depth-2 bias/K register prefetch in attention ONLY (bisect round).
// N=4096, D=512, H=8, DH=64, F=2048. fp32 in/out, bf16 MFMA internally.

typedef float f32x4 __attribute__((ext_vector_type(4)));
typedef short s8v  __attribute__((ext_vector_type(8)));   // 8 bf16 in 4 VGPRs
typedef unsigned short u16;

#define MFMA16(a,b,c) __builtin_amdgcn_mfma_f32_16x16x32_bf16((a),(b),(c),0,0,0)

static constexpr int N  = 4096;
static constexpr int D  = 512;
static constexpr int H  = 8;
static constexpr int F  = 2048;
static constexpr int QKVW = 3 * D;       // 1536
static constexpr int NH   = N * H;       // 32768 (bias row stride in floats)
static constexpr int QT   = 64;          // q-rows per attn block
static constexpr int MS   = 4;           // m-splits
static constexpr int ATTN_LDS = 65536;   // bias double buffer 2 x 32 KB

__device__ inline u16 f2bf(float f) {
  union { float f; unsigned u; } x; x.f = f;
  unsigned r = x.u + 0x7fffu + ((x.u >> 16) & 1u);
  return (u16)(r >> 16);
}

// ---------------- LayerNorm: fp32 (N,512) -> bf16 (N,512) ----------------
__global__ __launch_bounds__(256) void ln_kernel(const float* __restrict__ x,
                                                 const float* __restrict__ g,
                                                 const float* __restrict__ b,
                                                 u16* __restrict__ out) {
  const int row  = blockIdx.x * 4 + (threadIdx.x >> 6);
  const int lane = threadIdx.x & 63;
  const float4* xr = (const float4*)(x + (size_t)row * D);
  float4 v0 = xr[lane], v1 = xr[64 + lane];
  float s  = v0.x + v0.y + v0.z + v0.w + v1.x + v1.y + v1.z + v1.w;
  float ss = v0.x*v0.x + v0.y*v0.y + v0.z*v0.z + v0.w*v0.w
           + v1.x*v1.x + v1.y*v1.y + v1.z*v1.z + v1.w*v1.w;
  for (int off = 1; off < 64; off <<= 1) {
    s  += __shfl_xor(s,  off);
    ss += __shfl_xor(ss, off);
  }
  const float mu   = s * (1.0f / D);
  const float var  = ss * (1.0f / D) - mu * mu;
  const float rstd = rsqrtf(var + 1e-5f);
  const float4* g4 = (const float4*)g;
  const float4* b4 = (const float4*)b;
  float4 g0 = g4[lane], g1 = g4[64 + lane];
  float4 b0 = b4[lane], b1 = b4[64 + lane];
  u16* orow = out + (size_t)row * D;
  ushort4 o0, o1;
  o0.x = f2bf((v0.x - mu) * rstd * g0.x + b0.x);
  o0.y = f2bf((v0.y - mu) * rstd * g0.y + b0.y);
  o0.z = f2bf((v0.z - mu) * rstd * g0.z + b0.z);
  o0.w = f2bf((v0.w - mu) * rstd * g0.w + b0.w);
  o1.x = f2bf((v1.x - mu) * rstd * g1.x + b1.x);
  o1.y = f2bf((v1.y - mu) * rstd * g1.y + b1.y);
  o1.z = f2bf((v1.z - mu) * rstd * g1.z + b1.z);
  o1.w = f2bf((v1.w - mu) * rstd * g1.w + b1.w);
  ((ushort4*)orow)[lane]      = o0;
  ((ushort4*)orow)[64 + lane] = o1;
}

// ------------- weight transpose fp32 (R,C) -> bf16 (C,R) ----------------
__global__ void transpose_w(const float* __restrict__ src, u16* __restrict__ dst,
                            int R, int C) {
  int idx = blockIdx.x * 256 + threadIdx.x;
  if (idx < R * C) {
    int r = idx / C, c = idx - r * C;
    dst[(size_t)c * R + r] = f2bf(src[idx]);
  }
}

__global__ void pack_bqkv(const float* __restrict__ bq, const float* __restrict__ bk,
                          const float* __restrict__ bv, float* __restrict__ bqkv) {
  int i = blockIdx.x * 256 + threadIdx.x;
  if (i < QKVW) bqkv[i] = (i < D) ? bq[i] : (i < 2 * D) ? bk[i - D] : bv[i - 2 * D];
}

// ---- K fragment tiles: kt[mt][h][half][lane] (16B chunks), mt = m/16 ----
__global__ void make_ktiles(const u16* __restrict__ qkv, u16* __restrict__ kt) {
  int t = blockIdx.x * 256 + threadIdx.x;        // 262144 chunks
  int ln = t & 63, half = (t >> 6) & 1, h = (t >> 7) & 7, mt = t >> 10;
  int lr = ln & 15, lq = ln >> 4;
  const u16* src = qkv + (size_t)(mt * 16 + lr) * QKVW + D + h * 64 + half * 32 + lq * 8;
  *(int4*)(kt + (size_t)t * 8) = *(const int4*)src;
}

// ---- V^T fragment tiles: vt[mt][h][db][ln<32] ----
__global__ void make_vtiles(const u16* __restrict__ qkv, u16* __restrict__ vt) {
  int t = blockIdx.x * 256 + threadIdx.x;        // 262144 chunks
  int ln = t & 31, db = (t >> 5) & 3, h = (t >> 7) & 7, mt = t >> 10;
  int lr = ln & 15, lq = ln >> 4;
  s8v v;
#pragma unroll
  for (int e = 0; e < 8; e++)
    v[e] = (short)qkv[(size_t)(mt * 16 + lq * 8 + e) * QKVW + 2 * D + h * 64 + db * 16 + lr];
  *(s8v*)(vt + (size_t)t * 8) = v;
}

// -------------------- GEMM: C = A @ Bt^T (+epilogue) ---------------------
template <int MODE>
__global__ __launch_bounds__(256) void gemm_bt(const u16* __restrict__ A,
                                               const u16* __restrict__ Bt,
                                               const float* __restrict__ bias,
                                               const float* __restrict__ res,
                                               void* __restrict__ outv,
                                               int M, int Nn, int K) {
  __shared__ __align__(16) u16 As[128 * 32];
  __shared__ __align__(16) u16 Bs[128 * 32];
  const int t = threadIdx.x;
  const int lane = t & 63, w = t >> 6;
  const int wr = w >> 1, wc = w & 1;
  const int lr = lane & 15, lq = lane >> 4;
  const int r0 = blockIdx.y * 128, c0 = blockIdx.x * 128;
  const int rr = t >> 2, cc = (t & 3) * 8;
  f32x4 acc[4][4] = {};
  for (int k0 = 0; k0 < K; k0 += 32) {
    __syncthreads();
    *(s8v*)&As[rr * 32 + cc]        = *(const s8v*)&A[(size_t)(r0 + rr) * K + k0 + cc];
    *(s8v*)&As[(64 + rr) * 32 + cc] = *(const s8v*)&A[(size_t)(r0 + 64 + rr) * K + k0 + cc];
    *(s8v*)&Bs[rr * 32 + cc]        = *(const s8v*)&Bt[(size_t)(c0 + rr) * K + k0 + cc];
    *(s8v*)&Bs[(64 + rr) * 32 + cc] = *(const s8v*)&Bt[(size_t)(c0 + 64 + rr) * K + k0 + cc];
    __syncthreads();
    s8v af[4], bf[4];
#pragma unroll
    for (int m = 0; m < 4; m++) af[m] = *(const s8v*)&As[(wr * 64 + m * 16 + lr) * 32 + lq * 8];
#pragma unroll
    for (int n = 0; n < 4; n++) bf[n] = *(const s8v*)&Bs[(wc * 64 + n * 16 + lr) * 32 + lq * 8];
#pragma unroll
    for (int m = 0; m < 4; m++)
#pragma unroll
      for (int n = 0; n < 4; n++) acc[m][n] = MFMA16(af[m], bf[n], acc[m][n]);
  }
#pragma unroll
  for (int m = 0; m < 4; m++)
#pragma unroll
    for (int n = 0; n < 4; n++) {
      const int col = c0 + wc * 64 + n * 16 + lr;
      const float bcol = bias[col];
#pragma unroll
      for (int j = 0; j < 4; j++) {
        const int row = r0 + wr * 64 + m * 16 + lq * 4 + j;
        float v = acc[m][n][j] + bcol;
        if (MODE == 0) {
          ((u16*)outv)[(size_t)row * Nn + col] = f2bf(v);
        } else if (MODE == 1) {
          v = 0.5f * v * (1.0f + erff(v * 0.70710678118654752f));
          ((u16*)outv)[(size_t)row * Nn + col] = f2bf(v);
        } else {
          ((float*)outv)[(size_t)row * Nn + col] = v + res[(size_t)row * Nn + col];
        }
      }
    }
  (void)M;
}

// ----------------------- flash attention + bias --------------------------
// grid 256 = (qb 64) x (ms 4). block 512 thr = 8 waves; wave w = head.
// Depth-2 bias register prefetch (2-phase unrolled loop, static reg indexing).
__global__ __launch_bounds__(512, 2) void attn_kernel(const u16* __restrict__ qkv,
                                                      const u16* __restrict__ kt,
                                                      const u16* __restrict__ vt,
                                                      const float* __restrict__ bias,
                                                      float* __restrict__ ctxp,
                                                      float* __restrict__ ml) {
  extern __shared__ __align__(16) char smem[];
  const int tid = threadIdx.x, lane = tid & 63, w = tid >> 6;  // w = head
  const int lr = lane & 15, lq = lane >> 4;
  const int qb = blockIdx.x >> 2, ms = blockIdx.x & 3;
  const int q0 = qb * QT;
  const int mt0 = ms * 64;                    // base m-tile index (units of 16)

  // ---- Q fragments: qf[qc][half] (one-time loads) ----
  s8v qf[4][2];
#pragma unroll
  for (int qc = 0; qc < 4; qc++) {
    const u16* qp = qkv + (size_t)(q0 + qc * 16 + lr) * QKVW + w * 64 + lq * 8;
    qf[qc][0] = *(const s8v*)qp;
    qf[qc][1] = *(const s8v*)(qp + 32);
  }

  f32x4 cacc[4][4] = {};                       // [qc][db]
  float mrun[4], lsum[4];
#pragma unroll
  for (int qc = 0; qc < 4; qc++) { mrun[qc] = -1e30f; lsum[qc] = 0.0f; }

  // ---- bias staging: regs -> LDS [h=8][q=64][m=16] f32, chunk-swizzled ----
  auto load_bias = [&](f32x4* br, int t) {
#pragma unroll
    for (int c4 = 0; c4 < 4; c4++) {
      int g = c4 * 512 + tid;
      int q = g >> 5, m = (g >> 1) & 15, h0 = (g & 1) * 4;
      br[c4] = *(const f32x4*)(bias + (size_t)(q0 + q) * NH
                               + (size_t)((mt0 + t) * 16 + m) * H + h0);
    }
  };
  auto write_bias = [&](const f32x4* br, int buf) {
    float* bl = (float*)(smem + buf * 32768);
#pragma unroll
    for (int c4 = 0; c4 < 4; c4++) {
      int g = c4 * 512 + tid;
      int q = g >> 5, m = (g >> 1) & 15, h0 = (g & 1) * 4;
      int slot = (m >> 2) ^ (q & 3);
#pragma unroll
      for (int e = 0; e < 4; e++)
        bl[(h0 + e) * 1024 + q * 16 + slot * 4 + (m & 3)] = br[c4][e];
    }
  };
  auto load_k = [&](s8v& k0, s8v& k1, int mt) {
    const u16* kp = kt + ((size_t)(mt * 8 + w) * 2) * 512 + lane * 8;
    k0 = *(const s8v*)kp;
    k1 = *(const s8v*)(kp + 512);
  };
  auto do_tile = [&](int t, int buf, s8v k0, s8v k1) {
    const int mt = mt0 + t;
    // QK^T: S^T[m 16][q 64]
    f32x4 sacc[4] = {};
#pragma unroll
    for (int qc = 0; qc < 4; qc++) {
      sacc[qc] = MFMA16(k0, qf[qc][0], sacc[qc]);
      sacc[qc] = MFMA16(k1, qf[qc][1], sacc[qc]);
    }
    // V fragments (issue early; used after softmax)
    s8v vf[4];
    const u16* vp = vt + ((size_t)(mt * 8 + w) * 4) * 256 + (lane & 31) * 8;
#pragma unroll
    for (int db = 0; db < 4; db++) vf[db] = *(const s8v*)(vp + (size_t)db * 256);

    const float* bl = (const float*)(smem + buf * 32768);
#pragma unroll
    for (int qc = 0; qc < 4; qc++) {
      const int q = qc * 16 + lr;
      f32x4 b4 = *(const f32x4*)(bl + w * 1024 + q * 16 + (lq ^ (q & 3)) * 4);
      float p4[4];
      float tmax = -1e30f;
#pragma unroll
      for (int j = 0; j < 4; j++) {
        float sv = sacc[qc][j] * 0.125f + b4[j];
        p4[j] = sv;
        tmax = fmaxf(tmax, sv);
      }
      tmax = fmaxf(tmax, __shfl_xor(tmax, 16));
      tmax = fmaxf(tmax, __shfl_xor(tmax, 32));
      if (!__all(tmax <= mrun[qc])) {          // T13: skip no-op rescale
        float mnew = fmaxf(mrun[qc], tmax);
        float sc = __expf(mrun[qc] - mnew);
        mrun[qc] = mnew;
        lsum[qc] *= sc;
#pragma unroll
        for (int db = 0; db < 4; db++) cacc[qc][db] *= sc;
      }
      float psum = 0.0f;
#pragma unroll
      for (int j = 0; j < 4; j++) { p4[j] = __expf(p4[j] - mrun[qc]); psum += p4[j]; }
      lsum[qc] += psum;
      // pack P -> bf16 B-fragment (k = m, 16 effective of 32)
      unsigned u0, u1;
      asm("v_cvt_pk_bf16_f32 %0, %1, %2" : "=v"(u0) : "v"(p4[0]), "v"(p4[1]));
      asm("v_cvt_pk_bf16_f32 %0, %1, %2" : "=v"(u1) : "v"(p4[2]), "v"(p4[3]));
      union { unsigned u[4]; s8v v; } pa;
#pragma unroll
      for (int r = 0; r < 4; r++) {
        int lqp = (2 * lq + (r >> 1)) & 3;
        unsigned gg = (unsigned)__shfl((int)((r & 1) ? u1 : u0), lr | (lqp << 4));
        pa.u[r] = (lq < 2) ? gg : 0u;
      }
#pragma unroll
      for (int db = 0; db < 4; db++) cacc[qc][db] = MFMA16(vf[db], pa.v, cacc[qc][db]);
    }
  };

  f32x4 bregA[4], bregB[4];
  s8v kA0, kA1, kB0, kB1;

  // prologue: tiles 0,1 in flight; buf0 <- tile 0
  load_bias(bregA, 0);
  load_bias(bregB, 1);
  load_k(kA0, kA1, mt0);
  write_bias(bregA, 0);
  __syncthreads();

  for (int tt = 0; tt < 32; tt++) {
    const int t0 = tt * 2, t1 = t0 + 1;
    // even phase: consume (t0, buf0, kA); bregB holds tile t0+1
    if (t0 + 2 < 64) load_bias(bregA, t0 + 2);
    load_k(kB0, kB1, mt0 + t1);
    do_tile(t0, 0, kA0, kA1);
    write_bias(bregB, 1);
    __syncthreads();
    // odd phase: consume (t1, buf1, kB); bregA holds tile t1+1
    if (t1 + 2 < 64) load_bias(bregB, t1 + 2);
    if (t1 + 1 < 64) load_k(kA0, kA1, mt0 + t1 + 1);
    do_tile(t1, 1, kB0, kB1);
    if (t1 + 1 < 64) write_bias(bregA, 0);
    __syncthreads();
  }

  // ---- finalize: reduce lsum over lq; write partials ----
#pragma unroll
  for (int qc = 0; qc < 4; qc++) {
    lsum[qc] += __shfl_xor(lsum[qc], 16);
    lsum[qc] += __shfl_xor(lsum[qc], 32);
  }
  if (lq == 0) {
#pragma unroll
    for (int qc = 0; qc < 4; qc++) {
      float2 v = make_float2(mrun[qc], lsum[qc]);
      *(float2*)(ml + (((size_t)ms * N + q0 + qc * 16 + lr) * H + w) * 2) = v;
    }
  }
#pragma unroll
  for (int qc = 0; qc < 4; qc++)
#pragma unroll
    for (int db = 0; db < 4; db++) {
      const size_t q = q0 + qc * 16 + lr;
      *(f32x4*)(ctxp + ((size_t)ms * N + q) * D + w * 64 + db * 16 + lq * 4)
          = cacc[qc][db];
    }
}

// ---- merge the 4 m-split partials -> ctx bf16 (N,512) ----
__global__ __launch_bounds__(256) void attn_merge(const float* __restrict__ ctxp,
                                                  const float* __restrict__ ml,
                                                  u16* __restrict__ ctx) {
  int idx = blockIdx.x * 256 + threadIdx.x;     // N * 128
  int q = idx >> 7, c = idx & 127;
  int d0 = c * 4, h = c >> 4;
  float m_[MS], l_[MS], M = -1e30f;
#pragma unroll
  for (int s = 0; s < MS; s++) {
    float2 v = *(const float2*)(ml + (((size_t)s * N + q) * H + h) * 2);
    m_[s] = v.x; l_[s] = v.y;
    M = fmaxf(M, v.x);
  }
  float L = 0.0f, w_[MS];
#pragma unroll
  for (int s = 0; s < MS; s++) { w_[s] = __expf(m_[s] - M); L += l_[s] * w_[s]; }
  const float inv = 1.0f / L;
  f32x4 o = {0.0f, 0.0f, 0.0f, 0.0f};
#pragma unroll
  for (int s = 0; s < MS; s++) {
    f32x4 p = *(const f32x4*)(ctxp + ((size_t)s * N + q) * D + d0);
#pragma unroll
    for (int j = 0; j < 4; j++) o[j] += p[j] * w_[s];
  }
  ushort4 r;
  r.x = f2bf(o[0] * inv); r.y = f2bf(o[1] * inv);
  r.z = f2bf(o[2] * inv); r.w = f2bf(o[3] * inv);
  *(ushort4*)(ctx + (size_t)q * D + d0) = r;
}

// ------------------------------- launch ----------------------------------
extern "C" void kernel_launch(void* const* d_in, const int* in_sizes, int n_in,
                              void* d_out, int out_size, void* d_ws, size_t ws_size,
                              hipStream_t stream) {
  const float* x    = (const float*)d_in[0];
  const float* abias= (const float*)d_in[1];
  const float* ln1g = (const float*)d_in[2];
  const float* ln1b = (const float*)d_in[3];
  const float* wq   = (const float*)d_in[4];
  const float* bq   = (const float*)d_in[5];
  const float* wk   = (const float*)d_in[6];
  const float* bk   = (const float*)d_in[7];
  const float* wv   = (const float*)d_in[8];
  const float* bv   = (const float*)d_in[9];
  const float* wo   = (const float*)d_in[10];
  const float* bo   = (const float*)d_in[11];
  const float* ln2g = (const float*)d_in[12];
  const float* ln2b = (const float*)d_in[13];
  const float* w1   = (const float*)d_in[14];
  const float* b1   = (const float*)d_in[15];
  const float* w2   = (const float*)d_in[16];
  const float* b2   = (const float*)d_in[17];
  float* out = (float*)d_out;

  char* ws = (char*)d_ws;
  size_t off = 0;
  auto alloc = [&](size_t bytes) { size_t o = off; off = (off + bytes + 255) & ~(size_t)255; return (void*)(ws + o); };
  u16*   xn    = (u16*)alloc((size_t)N * D * 2);
  u16*   qkv   = (u16*)alloc((size_t)N * QKVW * 2);
  u16*   ktl   = (u16*)alloc((size_t)N * D * 2);
  u16*   vtl   = (u16*)alloc((size_t)N * D * 2);
  u16*   ctx   = (u16*)alloc((size_t)N * D * 2);
  float* x2    = (float*)alloc((size_t)N * D * 4);
  u16*   xn2   = (u16*)alloc((size_t)N * D * 2);
  u16*   hb    = (u16*)alloc((size_t)N * F * 2);
  u16*   WqkvT = (u16*)alloc((size_t)QKVW * D * 2);
  u16*   WoT   = (u16*)alloc((size_t)D * D * 2);
  u16*   W1T   = (u16*)alloc((size_t)F * D * 2);
  u16*   W2T   = (u16*)alloc((size_t)D * F * 2);
  float* bqkv  = (float*)alloc((size_t)QKVW * 4);
  float* ctxp  = (float*)alloc((size_t)MS * N * D * 4);   // 32 MB partials
  float* ml    = (float*)alloc((size_t)MS * N * H * 2 * 4);

  hipFuncSetAttribute((const void*)attn_kernel,
                      hipFuncAttributeMaxDynamicSharedMemorySize, ATTN_LDS);

  // weight prep
  transpose_w<<<(D * D + 255) / 256, 256, 0, stream>>>(wq, WqkvT, D, D);
  transpose_w<<<(D * D + 255) / 256, 256, 0, stream>>>(wk, WqkvT + D * D, D, D);
  transpose_w<<<(D * D + 255) / 256, 256, 0, stream>>>(wv, WqkvT + 2 * D * D, D, D);
  transpose_w<<<(D * D + 255) / 256, 256, 0, stream>>>(wo, WoT, D, D);
  transpose_w<<<(D * F + 255) / 256, 256, 0, stream>>>(w1, W1T, D, F);
  transpose_w<<<(F * D + 255) / 256, 256, 0, stream>>>(w2, W2T, F, D);
  pack_bqkv<<<(QKVW + 255) / 256, 256, 0, stream>>>(bq, bk, bv, bqkv);

  // LN1 -> QKV
  ln_kernel<<<N / 4, 256, 0, stream>>>(x, ln1g, ln1b, xn);
  gemm_bt<0><<<dim3(QKVW / 128, N / 128), 256, 0, stream>>>(xn, WqkvT, bqkv, nullptr, qkv, N, QKVW, D);
  // K/V fragment tiles
  make_ktiles<<<1024, 256, 0, stream>>>(qkv, ktl);
  make_vtiles<<<1024, 256, 0, stream>>>(qkv, vtl);
  // attention: 256 blocks = 64 q-blocks x 4 m-splits, then merge
  attn_kernel<<<(N / QT) * MS, 512, ATTN_LDS, stream>>>(qkv, ktl, vtl, abias, ctxp, ml);
  attn_merge<<<(N * 128) / 256, 256, 0, stream>>>(ctxp, ml, ctx);
  // O proj + residual -> x2 (fp32)
  gemm_bt<2><<<dim3(D / 128, N / 128), 256, 0, stream>>>(ctx, WoT, bo, x, x2, N, D, D);
  // LN2 -> FFN
  ln_kernel<<<N / 4, 256, 0, stream>>>(x2, ln2g, ln2b, xn2);
  gemm_bt<1><<<dim3(F / 128, N / 128), 256, 0, stream>>>(xn2, W1T, b1, nullptr, hb, N, F, D);
  gemm_bt<2><<<dim3(D / 128, N / 128), 256, 0, stream>>>(hb, W2T, b2, x2, out, N, D, F);
  (void)in_sizes; (void)n_in; (void)out_size; (void)ws_size;
}